// Round 9
// baseline (119.511 us; speedup 1.0000x reference)
//
#include <hip/hip_runtime.h>
#include <hip/hip_bf16.h>
#include <stdint.h>

typedef __attribute__((ext_vector_type(8))) short short8;
typedef __attribute__((ext_vector_type(4))) float f32x4;
typedef unsigned short u16;

#define AS1 __attribute__((address_space(1)))
#define AS3 __attribute__((address_space(3)))

__device__ __forceinline__ u16 f2b(float f) {
  union { float f; uint32_t u; } c; c.f = f;
  uint32_t u = c.u;
  return (u16)((u + 0x7fffu + ((u >> 16) & 1u)) >> 16);  // RNE
}
__device__ __forceinline__ float b2f(u16 b) {
  union { uint32_t u; float f; } c; c.u = ((uint32_t)b) << 16;
  return c.f;
}

// ---------------- conversion kernels (verified round 1) ----------------
__global__ void cvt_bf16_kernel(const float* __restrict__ src,
                                u16* __restrict__ dst, int n4) {
  int i = blockIdx.x * blockDim.x + threadIdx.x;
  if (i >= n4) return;
  const float4 v = reinterpret_cast<const float4*>(src)[i];
  ushort4 o;
  o.x = f2b(v.x); o.y = f2b(v.y); o.z = f2b(v.z); o.w = f2b(v.w);
  reinterpret_cast<ushort4*>(dst)[i] = o;
}

__global__ void cvt_transpose_kernel(const float* __restrict__ w0,
                                     const float* __restrict__ w1,
                                     const float* __restrict__ w2,
                                     u16* __restrict__ d0,
                                     u16* __restrict__ d1,
                                     u16* __restrict__ d2,
                                     int K, int N) {
  const float* src = (blockIdx.y == 0) ? w0 : (blockIdx.y == 1 ? w1 : w2);
  u16* dst = (blockIdx.y == 0) ? d0 : (blockIdx.y == 1 ? d1 : d2);
  int idx = blockIdx.x * blockDim.x + threadIdx.x;
  if (idx >= K * N) return;
  int k = idx / N, n = idx - k * N;
  dst[(size_t)n * K + k] = f2b(src[idx]);
}

// -------- 8-phase, register-pipelined (reads one phase ahead) GEMM --------
// Byte-identical to round 6 EXCEPT __launch_bounds__(512, 2): r6's (512,1)
// is degenerate for a 512-thread block (k = 1*4/8 = 0.5 blocks/CU), which
// made the compiler clamp to a 128-VGPR target and spill the ~240-reg
// pipeline (r6 counters: VGPR_Count=128, WRITE_SIZE 33->59.7 MB).  (512,2)
// declares exactly our LDS-bound occupancy (1 block/CU, 2 waves/SIMD) and
// raises the cap to 256 VGPR.
// Schedule (passed correctness in r6, absmax 0.03125): each phase p does
// [lgkm0(waits reads issued @p-1); issue ds_reads for p+1; issue stages;
// sched_barrier; MFMA(p) on regs loaded @p-1; (VMW); barrier] -> LDS pipe
// crunches p+1's reads UNDER MFMA(p).  Register sets rotate: aA=LO, aB=HI;
// bA/bB = b01 even/odd tile, bC = b23 shared.
// Read-issues: ph0:bC(d0) ph1:aB(d0) ph3:aA,bB(d1) ph4:bC(d1) ph5:aB(d1)
// ph7:aA,bA(d0,tile e').  Stage stream (e'=2j+2, o'=2j+3): ph2:B(e')
// ph3:A0(e') ph4:A1(e') ph6:B0(o') ph7:[B1(o')],A0(o'),A1(o').
// WAR: d0-B written ph2 (last read-issue ph0); d0-A ph3/4 (last ph1);
// d1-B ph6/7 (last ph4); d1-A ph7 (last ph5) — all barrier-separated.
// Deadlines: tile-odd landed by ph2-end VMW(4|2) (leaves only ph2's own);
// tile e' by ph6-end VMW(2) (drains through ph4).  Last iter drains 0.

#define BAR() do { __builtin_amdgcn_s_barrier(); __builtin_amdgcn_sched_barrier(0); } while (0)
#define SB() __builtin_amdgcn_sched_barrier(0)
#define LGKM0() do { asm volatile("s_waitcnt lgkmcnt(0)" ::: "memory"); __builtin_amdgcn_sched_barrier(0); } while (0)
#define VMW(n) do { asm volatile("s_waitcnt vmcnt(" #n ")" ::: "memory"); __builtin_amdgcn_sched_barrier(0); } while (0)

template <int GATES>
__global__ __launch_bounds__(512, 2) void gemm8_kernel(
    const u16* __restrict__ a1,    // A cols 0..511    [16384,512] bf16
    const u16* __restrict__ a2,    // A cols 512..1023 [16384,512] bf16
    const u16* __restrict__ wt,    // weights^T [N][1024] bf16
    const u16* __restrict__ hb,    // h_prev bf16 [16384,512]
    const u16* __restrict__ zb_in, // z bf16 (cand)
    u16* __restrict__ o_z,         // gates
    u16* __restrict__ o_rh,        // gates
    float* __restrict__ o_f) {     // cand
  constexpr int NT = 16;
  constexpr int NITER = 8;
  constexpr int BN = GATES ? 256 : 128;
  constexpr int MQ = GATES ? 4 : 2;            // a-frags per half
  constexpr int AHALF = GATES ? 16384 : 8192;  // per-wave A wm-stride bytes
  constexpr int DBUF_E = GATES ? 32768 : 24576;
  constexpr int DB1B = DBUF_E * 2;             // dbuf1 byte offset

  __shared__ u16 lds[2 * DBUF_E];
  const char* ldsb = (const char*)lds;

  const int tid = threadIdx.x;
  const int lane = tid & 63;
  const int wid = tid >> 6;
  const int wm = GATES ? (wid >> 2) : (wid >> 1);
  const int wn = GATES ? (wid & 3) : (wid & 1);

  // XCD-chunked bijective swizzle (grid 256 = 8*32)
  const int wg = ((int)blockIdx.x & 7) * 32 + ((int)blockIdx.x >> 3);
  const int bn = wg & 3;
  const int bm = wg >> 2;

  // ---- staging (verified r5): one inst = 512 lanes x 16B = 64 rows x 128B
  const int srow8 = tid >> 3;
  const int swzb = ((tid & 7) ^ (srow8 & 7)) << 4;
  auto STAGE = [&](int t, int kind) {
    if (t >= NT) return;
    u16* dst = lds + (t & 1) * DBUF_E + kind * 8192 + wid * 512;
    if (kind < 2) {  // A half
      const char* src = ((t < 8) ? ((const char*)a1 + (size_t)t * 128)
                                 : ((const char*)a2 + (size_t)(t - 8) * 128)) +
                        (size_t)(bm * 256 + kind * 128 + srow8) * 1024 + swzb;
      __builtin_amdgcn_global_load_lds((const AS1 void*)src, (AS3 void*)dst, 16, 0, 0);
      __builtin_amdgcn_global_load_lds((const AS1 void*)(src + 65536), (AS3 void*)(dst + 4096), 16, 0, 0);
    } else {         // B half
      const char* src = (const char*)wt +
                        (size_t)(bn * BN + (kind - 2) * 128 + srow8) * 2048 +
                        (size_t)t * 128 + swzb;
      __builtin_amdgcn_global_load_lds((const AS1 void*)src, (AS3 void*)dst, 16, 0, 0);
      __builtin_amdgcn_global_load_lds((const AS1 void*)(src + 131072), (AS3 void*)(dst + 4096), 16, 0, 0);
    }
  };

  // ---- frag-read addressing (verified r5)
  const int rsel = lane & 15;
  const int kg = lane >> 4;
  const int sl0 = (kg ^ (rsel & 7)) << 4;
  const int sl1 = ((4 + kg) ^ (rsel & 7)) << 4;
  const int aoff0 = wm * AHALF + rsel * 128;
  const int boff0 = 32768 + wn * 8192 + rsel * 128;

  f32x4 acc[2 * MQ][4] = {};
  short8 aA[MQ][2], aB[MQ][2];        // A LO / HI halves
  short8 bA[2][2], bB[2][2], bC[2][2];  // b01 even / b01 odd / b23 shared

  auto RD_A = [&](auto& dst, int DB, int mfb) {
#pragma unroll
    for (int mi = 0; mi < MQ; ++mi) {
      dst[mi][0] = *(const short8*)(ldsb + DB + aoff0 + (mfb + mi) * 2048 + sl0);
      dst[mi][1] = *(const short8*)(ldsb + DB + aoff0 + (mfb + mi) * 2048 + sl1);
    }
  };
  auto RD_B = [&](auto& dst, int DB, int nfb) {
#pragma unroll
    for (int ni = 0; ni < 2; ++ni) {
      dst[ni][0] = *(const short8*)(ldsb + DB + boff0 + (nfb + ni) * 2048 + sl0);
      dst[ni][1] = *(const short8*)(ldsb + DB + boff0 + (nfb + ni) * 2048 + sl1);
    }
  };
  auto MM = [&](auto& A, auto& Bv, int mb, int nb) {
    __builtin_amdgcn_s_setprio(1);
#pragma unroll
    for (int mi = 0; mi < MQ; ++mi)
#pragma unroll
      for (int ni = 0; ni < 2; ++ni) {
        acc[mb + mi][nb + ni] = __builtin_amdgcn_mfma_f32_16x16x32_bf16(A[mi][0], Bv[ni][0], acc[mb + mi][nb + ni], 0, 0, 0);
        acc[mb + mi][nb + ni] = __builtin_amdgcn_mfma_f32_16x16x32_bf16(A[mi][1], Bv[ni][1], acc[mb + mi][nb + ni], 0, 0, 0);
      }
    __builtin_amdgcn_s_setprio(0);
  };

  // ---- prologue: tile0 fully + tile1 fully in flight; wait tile0 only
  STAGE(0, 2); if constexpr (GATES) STAGE(0, 3);
  STAGE(0, 0); STAGE(0, 1);
  STAGE(1, 2); if constexpr (GATES) STAGE(1, 3);
  STAGE(1, 0); STAGE(1, 1);
  if constexpr (GATES) VMW(8); else VMW(6);
  BAR();
  RD_A(aA, 0, 0); RD_B(bA, 0, 0);

#pragma unroll 1
  for (int j = 0; j < NITER; ++j) {
    const int e2 = 2 * j + 2, o2 = 2 * j + 3;
    const bool stg = e2 < NT;
    // ph0: MFMA(aA,bA) tile-even; read b23(d0)
    LGKM0(); RD_B(bC, 0, 2); SB();
    MM(aA, bA, 0, 0); BAR();
    // ph1: read aHI(d0)
    LGKM0(); RD_A(aB, 0, MQ); SB();
    MM(aA, bC, 0, 2); BAR();
    // ph2: stage B(e'); VMW -> tile-odd landed
    LGKM0();
    if (stg) { STAGE(e2, 2); if constexpr (GATES) STAGE(e2, 3); }
    SB();
    MM(aB, bC, MQ, 2);
    if (stg) { if constexpr (GATES) VMW(4); else VMW(2); } else VMW(0);
    BAR();
    // ph3: read aLO,b01 (d1); stage A0(e')
    LGKM0(); RD_A(aA, DB1B, 0); RD_B(bB, DB1B, 0);
    if (stg) STAGE(e2, 0);
    SB();
    MM(aB, bA, MQ, 0); BAR();
    // ph4: read b23(d1); stage A1(e')
    LGKM0(); RD_B(bC, DB1B, 2);
    if (stg) STAGE(e2, 1);
    SB();
    MM(aA, bB, 0, 0); BAR();
    // ph5: read aHI(d1)
    LGKM0(); RD_A(aB, DB1B, MQ); SB();
    MM(aA, bC, 0, 2); BAR();
    // ph6: stage B0(o'); VMW -> tile e' landed
    LGKM0();
    if (o2 < NT) STAGE(o2, 2);
    SB();
    MM(aB, bC, MQ, 2);
    if (stg) VMW(2); else VMW(0);
    BAR();
    // ph7: read aLO,b01 (d0, tile e'); stage rest of o'
    LGKM0();
    if (j < NITER - 1) { RD_A(aA, 0, 0); RD_B(bA, 0, 0); }
    if (o2 < NT) { if constexpr (GATES) STAGE(o2, 3); STAGE(o2, 0); STAGE(o2, 1); }
    SB();
    MM(aB, bB, MQ, 0); BAR();
  }

  // ---- epilogue.  C/D: col=rsel, row=kg*4+q (verified r3).
  const int row0 = bm * 256 + wm * (GATES ? 128 : 64) + kg * 4;
  const int col0 = bn * BN + wn * 64 + rsel;
  if constexpr (GATES) {
    if (bn < 2) {  // z half (global cols 0..511), block-uniform
#pragma unroll
      for (int mf = 0; mf < 8; ++mf)
#pragma unroll
        for (int nf = 0; nf < 4; ++nf)
#pragma unroll
          for (int q = 0; q < 4; ++q) {
            const int row = row0 + mf * 16 + q;
            const int col = col0 + nf * 16;
            const float zf = 1.f / (1.f + __expf(-acc[mf][nf][q]));
            o_z[(size_t)row * 512 + col] = f2b(zf);
          }
    } else {       // r half (global cols 512..1023)
#pragma unroll
      for (int mf = 0; mf < 8; ++mf)
#pragma unroll
        for (int nf = 0; nf < 4; ++nf)
#pragma unroll
          for (int q = 0; q < 4; ++q) {
            const int row = row0 + mf * 16 + q;
            const int col = col0 + nf * 16 - 512;
            const size_t idx = (size_t)row * 512 + col;
            const float rf = 1.f / (1.f + __expf(-acc[mf][nf][q]));
            o_rh[idx] = f2b(rf * b2f(hb[idx]));
          }
    }
  } else {
#pragma unroll
    for (int mf = 0; mf < 4; ++mf)
#pragma unroll
      for (int nf = 0; nf < 4; ++nf)
#pragma unroll
        for (int q = 0; q < 4; ++q) {
          const int row = row0 + mf * 16 + q;
          const int col = col0 + nf * 16;
          const size_t idx = (size_t)row * 512 + col;
          const float s = acc[mf][nf][q];
          const float hh = 2.f / (1.f + __expf(-2.f * s)) - 1.f;  // tanh
          const float z = b2f(zb_in[idx]);
          o_f[idx] = z * b2f(hb[idx]) + (1.f - z) * hh;
        }
  }
}

// ---------------- launch ----------------
extern "C" void kernel_launch(void* const* d_in, const int* in_sizes, int n_in,
                              void* d_out, int out_size, void* d_ws, size_t ws_size,
                              hipStream_t stream) {
  const float* inputs = (const float*)d_in[0];
  const float* h_prev = (const float*)d_in[1];
  const float* Wz = (const float*)d_in[2];
  const float* Wr = (const float*)d_in[3];
  const float* Wh = (const float*)d_in[4];
  float* out = (float*)d_out;

  const int B = 16384, D = 512, U = 512, K = 1024;

  u16* xb = (u16*)d_ws;                 // [B,D] bf16
  u16* hb = xb + (size_t)B * D;         // [B,U] bf16
  u16* wzt = hb + (size_t)B * U;        // [1024,1024]: rows 0-511 Wz^T, 512-1023 Wr^T
  u16* wrt = wzt + (size_t)K * U;
  u16* wht = wrt + (size_t)K * U;       // [512,1024] Wh^T
  u16* zb = wht + (size_t)K * U;        // [B,U] bf16
  u16* rhb = zb + (size_t)B * U;        // [B,U] bf16

  const int n4 = (B * D) / 4;
  cvt_bf16_kernel<<<(n4 + 255) / 256, 256, 0, stream>>>(inputs, xb, n4);
  cvt_bf16_kernel<<<(n4 + 255) / 256, 256, 0, stream>>>(h_prev, hb, n4);
  dim3 tg((K * U + 255) / 256, 3);
  cvt_transpose_kernel<<<tg, 256, 0, stream>>>(Wz, Wr, Wh, wzt, wrt, wht, K, U);

  // gates: N=1024 (z|r), BN=256 -> grid 256 blocks, full chip
  gemm8_kernel<1><<<dim3(256), 512, 0, stream>>>(xb, hb, wzt, hb, nullptr, zb, rhb, nullptr);
  // candidate: N=512, BN=128 -> grid 256 blocks, full chip
  gemm8_kernel<0><<<dim3(256), 512, 0, stream>>>(xb, rhb, wht, hb, zb, nullptr, nullptr, out);
}

// Round 10
// 101.488 us; speedup vs baseline: 1.1776x; 1.1776x over previous
//
#include <hip/hip_runtime.h>
#include <hip/hip_bf16.h>
#include <stdint.h>

typedef __attribute__((ext_vector_type(8))) short short8;
typedef __attribute__((ext_vector_type(4))) float f32x4;
typedef unsigned short u16;

#define AS1 __attribute__((address_space(1)))
#define AS3 __attribute__((address_space(3)))

__device__ __forceinline__ u16 f2b(float f) {
  union { float f; uint32_t u; } c; c.f = f;
  uint32_t u = c.u;
  return (u16)((u + 0x7fffu + ((u >> 16) & 1u)) >> 16);  // RNE
}
__device__ __forceinline__ float b2f(u16 b) {
  union { uint32_t u; float f; } c; c.u = ((uint32_t)b) << 16;
  return c.f;
}

// ---------------- conversion kernels (verified round 1) ----------------
__global__ void cvt_bf16_kernel(const float* __restrict__ src,
                                u16* __restrict__ dst, int n4) {
  int i = blockIdx.x * blockDim.x + threadIdx.x;
  if (i >= n4) return;
  const float4 v = reinterpret_cast<const float4*>(src)[i];
  ushort4 o;
  o.x = f2b(v.x); o.y = f2b(v.y); o.z = f2b(v.z); o.w = f2b(v.w);
  reinterpret_cast<ushort4*>(dst)[i] = o;
}

__global__ void cvt_transpose_kernel(const float* __restrict__ w0,
                                     const float* __restrict__ w1,
                                     const float* __restrict__ w2,
                                     u16* __restrict__ d0,
                                     u16* __restrict__ d1,
                                     u16* __restrict__ d2,
                                     int K, int N) {
  const float* src = (blockIdx.y == 0) ? w0 : (blockIdx.y == 1 ? w1 : w2);
  u16* dst = (blockIdx.y == 0) ? d0 : (blockIdx.y == 1 ? d1 : d2);
  int idx = blockIdx.x * blockDim.x + threadIdx.x;
  if (idx >= K * N) return;
  int k = idx / N, n = idx - k * N;
  dst[(size_t)n * K + k] = f2b(src[idx]);
}

// ---- 128x128 tile, 256 thr, register-prefetch-across-barrier GEMM ----
// C[16384,N] = A[.,1024] @ Wt[N][1024]^T.  BM=BN=128, BK=64, NT=16.
// 4 waves 2Mx2N, per-wave 64x64 (acc = 4x4 16x16 frags = 64 VGPR).
// LDS 64KB = 2 dbuf x (A 16KB + B 16KB) -> 2 blocks/CU (independent
// barrier groups fill each other's stalls).
// Schedule (the r6 mechanism at a register budget that FITS):
//   P0: issue RD b23(t); STG B(t+1,np); BAR; lgkm(4);  MFMA aLO.b01
//   P1: issue RD aHI(t); STG A(t+1,np); BAR; lgkm(4);  MFMA aLO.b23
//   P2:                                 BAR; lgkm(0);  MFMA aHI.b23
//   P3: VMW(0); BAR; issue RD aLO,b01(t+1,np);         MFMA aHI.b01
// Every MFMA consumes regs whose ds_reads were ISSUED >=1 phase earlier
// (counted lgkm leaves the just-issued reads in flight) -> DS pipe works
// under MFMA + barrier-wait instead of serializing after each barrier.
// Operand sets: aLO/aHI/b23 single, b01 ping-pong (E/O by tile parity).
//   ~170 VGPR total (acc 64 + operands 80 + addr).
// WAR: B(np) staged t.P0, last read-issue of that region t-1.P3 (1 barrier
// before); A(np) staged t.P1, last read t-1.P1 (4 barriers).  Reads of
// staged data: issued t.P3 AFTER all-wave VMW(0)+BAR -> landed, cross-wave
// safe.  lgkm counts (DS completes in-order): P0 outstanding 12 (8 from
// t-1.P3 + own 4) -> lgkm(4) drains prefetched aLO/b01; P1: 8 -> lgkm(4)
// drains b23, keeps aHI; P2: lgkm(0) drains aHI; P3 operands already
// drained, no wait.  Swizzle/numerics byte-identical to r5 (verified).

#define BAR() __builtin_amdgcn_s_barrier()
#define SB() __builtin_amdgcn_sched_barrier(0)
#define LG(n) do { asm volatile("s_waitcnt lgkmcnt(" #n ")" ::: "memory"); __builtin_amdgcn_sched_barrier(0); } while (0)
#define VMW(n) do { asm volatile("s_waitcnt vmcnt(" #n ")" ::: "memory"); __builtin_amdgcn_sched_barrier(0); } while (0)

template <int GATES>
__global__ __launch_bounds__(256, 2) void gemm_rp_kernel(
    const u16* __restrict__ a1,    // A cols 0..511    [16384,512] bf16
    const u16* __restrict__ a2,    // A cols 512..1023 [16384,512] bf16
    const u16* __restrict__ wt,    // weights^T [N][1024] bf16
    const u16* __restrict__ hb,    // h_prev bf16
    const u16* __restrict__ zb_in, // z bf16 (cand)
    u16* __restrict__ o_z,         // gates
    u16* __restrict__ o_rh,        // gates
    float* __restrict__ o_f) {     // cand
  constexpr int NT = 16;
  constexpr int BUF_E = 16384;     // u16 per dbuf (A 8192 + B 8192)

  __shared__ u16 lds[2 * BUF_E];
  const char* ldsb = (const char*)lds;

  const int tid = threadIdx.x;
  const int lane = tid & 63;
  const int wid = tid >> 6;        // 0..3
  const int wm = wid >> 1, wn = wid & 1;

  // XCD-chunked bijective swizzle
  const int nbn = GATES ? 8 : 4;
  const int cpx = GATES ? 128 : 64;            // grid/8
  const int wg = ((int)blockIdx.x & 7) * cpx + ((int)blockIdx.x >> 3);
  const int bn = wg & (nbn - 1);
  const int bm = wg / nbn;

  // ---- staging: one inst = 256 lanes x 16B = 4KB = 32 rows x 128B
  const int srow = tid >> 3;                               // 0..31
  const int swzb = ((tid & 7) ^ (srow & 7)) << 4;
  auto STG_A = [&](int t, u16* buf) {
    if (t >= NT) return;
    const char* base = (t < 8) ? ((const char*)a1 + (size_t)t * 128)
                               : ((const char*)a2 + (size_t)(t - 8) * 128);
#pragma unroll
    for (int i = 0; i < 4; ++i) {
      const char* src = base + (size_t)(bm * 128 + i * 32 + srow) * 1024 + swzb;
      __builtin_amdgcn_global_load_lds((const AS1 void*)src,
                                       (AS3 void*)(buf + i * 2048 + wid * 512), 16, 0, 0);
    }
  };
  auto STG_B = [&](int t, u16* buf) {
    if (t >= NT) return;
#pragma unroll
    for (int i = 0; i < 4; ++i) {
      const char* src = (const char*)wt +
                        (size_t)(bn * 128 + i * 32 + srow) * 2048 +
                        (size_t)t * 128 + swzb;
      __builtin_amdgcn_global_load_lds((const AS1 void*)src,
                                       (AS3 void*)(buf + 8192 + i * 2048 + wid * 512), 16, 0, 0);
    }
  };

  // ---- frag-read addressing (swizzled, verified r5 formulas)
  const int rsel = lane & 15;
  const int kg = lane >> 4;
  const int sl0 = (kg ^ (rsel & 7)) << 4;
  const int sl1 = ((4 + kg) ^ (rsel & 7)) << 4;
  const int aoff0 = (wm * 64 + rsel) * 128;
  const int boff0 = 16384 + (wn * 64 + rsel) * 128;

  f32x4 acc[4][4] = {};
  short8 aLO[2][2], aHI[2][2];      // A frags mf{0,1} / mf{2,3}
  short8 b01E[2][2], b01O[2][2];    // B frags nf{0,1}, even/odd tile sets
  short8 b23[2][2];                 // B frags nf{2,3}

  auto RD_A = [&](auto& dst, int bufB, int mfb) {
#pragma unroll
    for (int mi = 0; mi < 2; ++mi) {
      dst[mi][0] = *(const short8*)(ldsb + bufB + aoff0 + (mfb + mi) * 2048 + sl0);
      dst[mi][1] = *(const short8*)(ldsb + bufB + aoff0 + (mfb + mi) * 2048 + sl1);
    }
  };
  auto RD_B = [&](auto& dst, int bufB, int nfb) {
#pragma unroll
    for (int ni = 0; ni < 2; ++ni) {
      dst[ni][0] = *(const short8*)(ldsb + bufB + boff0 + (nfb + ni) * 2048 + sl0);
      dst[ni][1] = *(const short8*)(ldsb + bufB + boff0 + (nfb + ni) * 2048 + sl1);
    }
  };
  auto MM = [&](auto& A, auto& Bv, int mb, int nb) {
    __builtin_amdgcn_s_setprio(1);
#pragma unroll
    for (int ks = 0; ks < 2; ++ks)
#pragma unroll
      for (int mi = 0; mi < 2; ++mi)
#pragma unroll
        for (int ni = 0; ni < 2; ++ni)
          acc[mb + mi][nb + ni] = __builtin_amdgcn_mfma_f32_16x16x32_bf16(
              A[mi][ks], Bv[ni][ks], acc[mb + mi][nb + ni], 0, 0, 0);
    __builtin_amdgcn_s_setprio(0);
  };

  // ---- one tile = 4 phases; b01c = current parity set, b01n = next
  auto TILE = [&](int t, int pB, int npB, auto& b01c, auto& b01n) {
    u16* npbuf = lds + npB / 2;
    // P0
    RD_B(b23, pB, 2); STG_B(t + 1, npbuf); SB();
    BAR(); LG(4); MM(aLO, b01c, 0, 0);
    // P1
    RD_A(aHI, pB, 2); STG_A(t + 1, npbuf); SB();
    BAR(); LG(4); MM(aLO, b23, 0, 2);
    // P2
    BAR(); LG(0); MM(aHI, b23, 2, 2);
    // P3
    VMW(0); BAR();
    if (t + 1 < NT) { RD_A(aLO, npB, 0); RD_B(b01n, npB, 0); }
    SB();
    MM(aHI, b01c, 2, 0);
  };

  // ---- prologue: stage tile0, drain, pre-read aLO/b01 of tile0
  STG_B(0, lds); STG_A(0, lds);
  VMW(0); BAR();
  RD_A(aLO, 0, 0); RD_B(b01E, 0, 0); SB();

#pragma unroll 1
  for (int j = 0; j < 8; ++j) {
    TILE(2 * j, 0, 32768, b01E, b01O);
    TILE(2 * j + 1, 32768, 0, b01O, b01E);
  }

  // ---- epilogue.  C/D: col=rsel, row=kg*4+q (verified r3).
  const int row0 = bm * 128 + wm * 64 + kg * 4;
  const int col0 = bn * 128 + wn * 64 + rsel;
  if constexpr (GATES) {
    if (bn < 4) {  // z half (global cols 0..511), block-uniform
#pragma unroll
      for (int mf = 0; mf < 4; ++mf)
#pragma unroll
        for (int nf = 0; nf < 4; ++nf)
#pragma unroll
          for (int q = 0; q < 4; ++q) {
            const int row = row0 + mf * 16 + q;
            const int col = col0 + nf * 16;
            const float zf = 1.f / (1.f + __expf(-acc[mf][nf][q]));
            o_z[(size_t)row * 512 + col] = f2b(zf);
          }
    } else {       // r half (global cols 512..1023)
#pragma unroll
      for (int mf = 0; mf < 4; ++mf)
#pragma unroll
        for (int nf = 0; nf < 4; ++nf)
#pragma unroll
          for (int q = 0; q < 4; ++q) {
            const int row = row0 + mf * 16 + q;
            const int col = col0 + nf * 16 - 512;
            const size_t idx = (size_t)row * 512 + col;
            const float rf = 1.f / (1.f + __expf(-acc[mf][nf][q]));
            o_rh[idx] = f2b(rf * b2f(hb[idx]));
          }
    }
  } else {
#pragma unroll
    for (int mf = 0; mf < 4; ++mf)
#pragma unroll
      for (int nf = 0; nf < 4; ++nf)
#pragma unroll
        for (int q = 0; q < 4; ++q) {
          const int row = row0 + mf * 16 + q;
          const int col = col0 + nf * 16;
          const size_t idx = (size_t)row * 512 + col;
          const float s = acc[mf][nf][q];
          const float hh = 2.f / (1.f + __expf(-2.f * s)) - 1.f;  // tanh
          const float z = b2f(zb_in[idx]);
          o_f[idx] = z * b2f(hb[idx]) + (1.f - z) * hh;
        }
  }
}

// ---------------- launch ----------------
extern "C" void kernel_launch(void* const* d_in, const int* in_sizes, int n_in,
                              void* d_out, int out_size, void* d_ws, size_t ws_size,
                              hipStream_t stream) {
  const float* inputs = (const float*)d_in[0];
  const float* h_prev = (const float*)d_in[1];
  const float* Wz = (const float*)d_in[2];
  const float* Wr = (const float*)d_in[3];
  const float* Wh = (const float*)d_in[4];
  float* out = (float*)d_out;

  const int B = 16384, D = 512, U = 512, K = 1024;

  u16* xb = (u16*)d_ws;                 // [B,D] bf16
  u16* hb = xb + (size_t)B * D;         // [B,U] bf16
  u16* wzt = hb + (size_t)B * U;        // [1024,1024]: rows 0-511 Wz^T, 512-1023 Wr^T
  u16* wrt = wzt + (size_t)K * U;
  u16* wht = wrt + (size_t)K * U;       // [512,1024] Wh^T
  u16* zb = wht + (size_t)K * U;        // [B,U] bf16
  u16* rhb = zb + (size_t)B * U;        // [B,U] bf16

  const int n4 = (B * D) / 4;
  cvt_bf16_kernel<<<(n4 + 255) / 256, 256, 0, stream>>>(inputs, xb, n4);
  cvt_bf16_kernel<<<(n4 + 255) / 256, 256, 0, stream>>>(h_prev, hb, n4);
  dim3 tg((K * U + 255) / 256, 3);
  cvt_transpose_kernel<<<tg, 256, 0, stream>>>(Wz, Wr, Wh, wzt, wrt, wht, K, U);

  // gates: N=1024, 128 bm x 8 bn = 1024 blocks (2/CU resident)
  gemm_rp_kernel<1><<<dim3(1024), 256, 0, stream>>>(xb, hb, wzt, hb, nullptr, zb, rhb, nullptr);
  // candidate: N=512, 128 bm x 4 bn = 512 blocks (2/CU resident)
  gemm_rp_kernel<0><<<dim3(512), 256, 0, stream>>>(xb, rhb, wht, hb, zb, nullptr, nullptr, out);
}